// Round 1
// baseline (216.014 us; speedup 1.0000x reference)
//
#include <hip/hip_runtime.h>

// LSTM B=8192,T=256,I=1,H=50 via MFMA -- R17: 2-tiles-per-wave restructure.
// R16 (161us) was VALU+sync bound: 14 waves/block, post-barrier burst of
// 26 ds_read_b128/block-step, x-wave as 14th barrier participant.
// Key fact: the MFMA B operand (h fragment) is tile-independent, so one
// wave can own TWO 16x16 tiles sharing ONE pair of b128 reads:
//   - 7 waves/block (448 thr): waves 0..5 own tiles (2w, 2w+1); wave 6
//     owns tile 12 + the x-duty (prefetch x(t+1)/x(t+2), publish k=50).
//   - LDS read burst per block-step: 26 -> 14 b128 (halved critical path),
//   - barrier syncs 7 waves instead of 14, dedicated x-wave eliminated,
//   - 2 independent activation chains/wave -> ILP hides trans latency.
// Math per chain unchanged from R16 (rcp-fused, 7 quarter-rate ops):
//   c2' = [c2*D2 + 2L*(Eg-1)*D1] * rcp(D1*D2),  D1=1+Ef, D2=(Eg+1)(1+Ei)
//   h   = (Ec-1) * rcp((Ec+1)(1+Eo)),           Ec=exp2(clamp(c2'))
// W single-product fp16, pre-scaled (sigmoid rows -log2e, g rows +2log2e).
// h fp16 plane double-buffered, ONE barrier/step. Pad lanes (unit>=50)
// redirect to slots 54/55. Wave 6 computes aB on a dummy copy of whA
// (MFMA pipe is 15% utilized -- free) but SKIPS chain-B activations/store.

#define NTH 448          // 7 waves
#define TST 256
#define MB 16
#define NBLK 512
#define HR 72            // h row stride in halfs (16B-aligned b128 frag reads)
#define HSZ (MB * HR)    // 1152 halfs per buffer

#define LOG2E 1.44269504088896f

typedef __attribute__((ext_vector_type(8))) _Float16 half8;
typedef __attribute__((ext_vector_type(4))) float float4v;

__device__ __forceinline__ float rcp_(float v)  { return __builtin_amdgcn_rcpf(v); }
__device__ __forceinline__ float exp2_(float v) { return __builtin_amdgcn_exp2f(v); }
__device__ __forceinline__ unsigned short f16bits(float v) {
    _Float16 h = (_Float16)v;                 // RNE
    return *(unsigned short*)&h;
}

__global__ __launch_bounds__(NTH, 4) void lstm_mfma(
    const float* __restrict__ x,      // [8192][256]
    const float* __restrict__ W_ih,   // [200]
    const float* __restrict__ W_hh,   // [200][50]
    const float* __restrict__ b_ih,   // [200]
    const float* __restrict__ b_hh,   // [200]
    const float* __restrict__ W_lin,  // [50]
    const float* __restrict__ b_lin,  // [1]
    float* __restrict__ out)          // [8192]
{
    __shared__ __align__(16) unsigned short Hh[2 * HSZ];   // fp16 h, double-buffered

    const int tid  = threadIdx.x;
    const int wv   = tid >> 6;      // 0..6
    const int ln   = tid & 63;
    const int lrow = ln & 15;       // batch-in-block / A-row m / D col
    const int quad = ln >> 4;
    const int bbase = (int)blockIdx.x * MB;
    const bool w6 = (wv == 6);
    const int TA = w6 ? 12 : 2 * wv;        // first tile
    const int TB = 2 * wv + 1;              // second tile (unused for wave 6)

    // ---- W-operand fragments (two tiles per wave; one-time L2 reads).
    // Row gr=T*16+lrow -> unit j=gr>>2, gate g=gr&3, W row = g*50+j.
    // k = q2*32 + quad*8 + i; k=50 -> W_ih, k=51 -> bias; pad rows (j>=50) zero.
    // Pre-scale: sigmoid rows (g!=2) by -log2e, g rows by +2log2e.
    half8 whA[2], whB[2];
    {
        auto fill = [&](int T, half8* dst) {
            const int gr = T * 16 + lrow;
            const int j  = gr >> 2, g = gr & 3;
            const int row = g * 50 + j;             // only dereferenced when j<50
            const float scl = (g == 2) ? (2.0f * LOG2E) : (-LOG2E);
            #pragma unroll
            for (int q2 = 0; q2 < 2; ++q2) {
                half8 h8;
                #pragma unroll
                for (int i = 0; i < 8; ++i) {
                    const int k = q2 * 32 + quad * 8 + i;
                    float V = 0.0f;
                    if (j < 50) {
                        if (k < 50)       V = W_hh[row * 50 + k];
                        else if (k == 50) V = W_ih[row];
                        else if (k == 51) V = b_ih[row] + b_hh[row];
                    }
                    h8[i] = (_Float16)(V * scl);    // single fp16 product (RNE)
                }
                dst[q2] = h8;
            }
        };
        fill(TA, whA);
        if (!w6) fill(TB, whB);
        else     { whB[0] = whA[0]; whB[1] = whA[1]; }   // dummy (aB discarded)
    }

    // ---- init h: zeros both bufs; k=50 buf0 <- fp16(x(b,0)); k=51 <- 1.0 both
    for (int i = tid; i < HSZ; i += NTH)       // HSZ uints = 2*HSZ halfs
        ((unsigned int*)Hh)[i] = 0u;
    __syncthreads();
    if (tid < MB) {
        float xv = x[(bbase + tid) * TST + 0];
        Hh[tid * HR + 50] = f16bits(xv);
        Hh[tid * HR + 51] = 0x3C00;            // fp16(1.0), never rewritten
        Hh[HSZ + tid * HR + 51] = 0x3C00;
    }
    __syncthreads();

    float c2A = 0.0f, c2B = 0.0f;              // c in the x2log2e domain
    const unsigned short* Hr = &Hh[lrow * HR + quad * 8];  // frag read base
    int jwA = TA * 4 + quad;                   // unit chain A writes
    if (jwA >= 50) jwA = 52 + quad;            // pad redirect (54/55), wave 6 only
    const int jwB = TB * 4 + quad;             // <=47 for waves 0..5, no redirect
    unsigned short* HwA = &Hh[lrow * HR + jwA];
    unsigned short* HwB = &Hh[lrow * HR + jwB];
    const float* xr = &x[(bbase + lrow) * TST];            // wave-6 x read row
    const float4v z4 = {0.f, 0.f, 0.f, 0.f};               // zero C operand

    // activation chain: gates (ai,af,ag,ao) pre-scaled i/f/o by -L, g by +2L
    auto act = [&](const float4v a4, float& c2) -> unsigned short {
        const float Ei = exp2_(a4[0]);
        const float Ef = exp2_(a4[1]);
        const float Eg = exp2_(a4[2]);
        const float Eo = exp2_(a4[3]);
        const float D1 = 1.0f + Ef;
        const float D2 = (Eg + 1.0f) * (1.0f + Ei);
        const float R  = rcp_(D1 * D2);
        const float tg = (Eg - 1.0f) * D1;
        const float nm = fmaf(2.0f * LOG2E, tg, c2 * D2);
        c2 = fminf(nm * R, 120.0f);            // clamp: exp2 overflow guard
        const float Ec = exp2_(c2);
        const float R2 = rcp_((Ec + 1.0f) * (1.0f + Eo));
        return f16bits((Ec - 1.0f) * R2);
    };

    // one compute step, both tiles; one pair of b128 reads feeds 4 MFMAs
    auto step2 = [&](int roff, int woff) {
        const half8 b0 = *(const half8*)(Hr + roff);
        const half8 b1 = *(const half8*)(Hr + roff + 32);

        float4v aA = __builtin_amdgcn_mfma_f32_16x16x32_f16(whA[0], b0, z4, 0, 0, 0);
        aA = __builtin_amdgcn_mfma_f32_16x16x32_f16(whA[1], b1, aA, 0, 0, 0);
        float4v aB = __builtin_amdgcn_mfma_f32_16x16x32_f16(whB[0], b0, z4, 0, 0, 0);
        aB = __builtin_amdgcn_mfma_f32_16x16x32_f16(whB[1], b1, aB, 0, 0, 0);

        HwA[woff] = act(aA, c2A);              // unconditional (pad-redirected)
        if (!w6) HwB[woff] = act(aB, c2B);     // wave-uniform skip for wave 6
    };

    #pragma unroll 1
    for (int t2 = 0; t2 < TST / 2; ++t2) {
        // wave 6 prefetches both x values at iteration top (latency hidden
        // under its own tile-12 compute); publishes into the buffer the NEXT
        // step will read, before the barrier that protects it.
        float xA = 0.0f, xB = 0.0f;
        if (w6 && ln < 16) {
            xA = xr[2 * t2 + 1];
            xB = xr[(2 * t2 + 2) & 255];       // t2=127: loaded, never read
        }

        step2(0, HSZ);                         // even: read buf0, write buf1
        if (w6 && ln < 16)
            Hh[HSZ + lrow * HR + 50] = f16bits(xA);   // buf1 <- x(odd step)
        __syncthreads();                       // barrier 1 (even step done)

        step2(HSZ, 0);                         // odd:  read buf1, write buf0
        if (w6 && ln < 16)
            Hh[lrow * HR + 50] = f16bits(xB);         // buf0 <- x(even step)
        __syncthreads();                       // barrier 2 (odd step done)
    }

    // ---- epilogue: final h in buf 0 (t=255 wrote buf0)
    if (tid < MB) {
        float s = b_lin[0];
        #pragma unroll 10
        for (int k = 0; k < 50; ++k) {
            float hk = (float)(*(const _Float16*)&Hh[tid * HR + k]);
            s += hk * W_lin[k];
        }
        out[bbase + tid] = s;
    }
}

extern "C" void kernel_launch(void* const* d_in, const int* in_sizes, int n_in,
                              void* d_out, int out_size, void* d_ws, size_t ws_size,
                              hipStream_t stream) {
    const float* x     = (const float*)d_in[0];
    const float* W_ih  = (const float*)d_in[1];
    const float* W_hh  = (const float*)d_in[2];
    const float* b_ih  = (const float*)d_in[3];
    const float* b_hh  = (const float*)d_in[4];
    const float* W_lin = (const float*)d_in[5];
    const float* b_lin = (const float*)d_in[6];
    float* out = (float*)d_out;

    lstm_mfma<<<dim3(NBLK), dim3(NTH), 0, stream>>>(
        x, W_ih, W_hh, b_ih, b_hh, W_lin, b_lin, out);
}

// Round 2
// 209.099 us; speedup vs baseline: 1.0331x; 1.0331x over previous
//
#include <hip/hip_runtime.h>

// LSTM B=8192,T=256,I=1,H=50 via MFMA -- R18 = R16 champion (161us) +
// ANTI-PHASE BLOCK SKEW.
// Post-mortem R17: 2-tiles/wave (halved LDS reads, halved barrier waves)
// was NEUTRAL -> bottleneck is not LDS/barrier-count. Issue model fits:
// 26 chains/CU-step x ~142 cyc (7 quarter-rate trans = 112 + ~30 full-rate)
// / 4 SIMD = 923 cyc = 59% of the 1565-cyc step wall == measured VALUBusy.
// Remaining 40% = serial per-step tail (ds_read ~120 + MFMA ~60 + act chain
// ~250 + barrier) exposed because the 2 co-resident blocks PHASE-LOCK
// in-phase (barrier parking -> laggard catches up), and wall = worst CU.
// Fix: skew one block of each pair by ~half a step (s_sleep(9) ~576 cyc)
// so each block's tail hides under the other's trans burst. Key
// ((b>>8)^b)&1 splits pairs under both (b,b+256) and (2b,2b+1) pairings.
//
// Math (R16, rcp-fused, 7 quarter-rate ops/lane/step):
//   c2' = [c2*D2 + 2L*(Eg-1)*D1] * rcp(D1*D2),  D1=1+Ef, D2=(Eg+1)(1+Ei)
//   h   = (Ec-1) * rcp((Ec+1)(1+Eo)),           Ec=exp2(clamp(c2'))
// Structure (R12/R15): per block 16 batches; wave wv (0..12) owns tile T=wv;
// wave 13 = x-wave (prefetches x(t+1)/x(t+2), owns the k=50 x-column; compute
// waves have zero global ops / zero conditionals in the t-loop). Per step:
// D[208x16] = W[208x64] x h[64x16]; rows = unit*4+gate, cols = batches.
// C/D: lane (lrow=ln&15, quad=ln>>4) of tile T holds gates (i,f,g,o) of
// (batch=lrow, unit=4T+quad) -> activations in-register. W single-product
// fp16, pre-scaled (sigmoid rows by -log2e, g rows by +2log2e) so gates
// feed exp2 directly. h fp16 plane, double-buffered, ONE barrier/step.
// Pad lanes (unit>=50) store to pad slots 54/55. 2 blk/CU x 14 waves.

#define NTH 896
#define TST 256
#define MB 16
#define NBLK 512
#define HR 72            // h row stride in halfs (16B-aligned b128 frag reads)
#define HSZ (MB * HR)    // 1152 halfs per buffer

#define LOG2E 1.44269504088896f

typedef __attribute__((ext_vector_type(8))) _Float16 half8;
typedef __attribute__((ext_vector_type(4))) float float4v;

__device__ __forceinline__ float rcp_(float v)  { return __builtin_amdgcn_rcpf(v); }
__device__ __forceinline__ float exp2_(float v) { return __builtin_amdgcn_exp2f(v); }
__device__ __forceinline__ unsigned short f16bits(float v) {
    _Float16 h = (_Float16)v;                 // RNE
    return *(unsigned short*)&h;
}

__global__ __launch_bounds__(NTH, 7) void lstm_mfma(
    const float* __restrict__ x,      // [8192][256]
    const float* __restrict__ W_ih,   // [200]
    const float* __restrict__ W_hh,   // [200][50]
    const float* __restrict__ b_ih,   // [200]
    const float* __restrict__ b_hh,   // [200]
    const float* __restrict__ W_lin,  // [50]
    const float* __restrict__ b_lin,  // [1]
    float* __restrict__ out)          // [8192]
{
    __shared__ __align__(16) unsigned short Hh[2 * HSZ];   // fp16 h, double-buffered

    const int tid  = threadIdx.x;
    const int wv   = tid >> 6;      // 0..12 = tile T; 13 = x-wave
    const int ln   = tid & 63;
    const int lrow = ln & 15;       // batch-in-block / A-row m / D col
    const int quad = ln >> 4;
    const int bbase = (int)blockIdx.x * MB;
    const int T = wv;

    // ---- W-operand fragments (one tile per wave; one-time L2 reads).
    // Row gr=T*16+lrow -> unit j=gr>>2, gate g=gr&3, W row = g*50+j.
    // k = q2*32 + quad*8 + i; k=50 -> W_ih, k=51 -> bias; pad rows (j>=50)
    // zero (incl. wave 13 -- it never issues MFMA).
    // Pre-scale: sigmoid rows (g!=2) by -log2e, g rows by +2log2e.
    half8 wh[2];
    {
        const int gr = T * 16 + lrow;
        const int j  = gr >> 2, g = gr & 3;
        const int row = g * 50 + j;             // only dereferenced when j<50
        const float scl = (g == 2) ? (2.0f * LOG2E) : (-LOG2E);
        #pragma unroll
        for (int q2 = 0; q2 < 2; ++q2) {
            half8 h8;
            #pragma unroll
            for (int i = 0; i < 8; ++i) {
                const int k = q2 * 32 + quad * 8 + i;
                float V = 0.0f;
                if (j < 50) {
                    if (k < 50)       V = W_hh[row * 50 + k];
                    else if (k == 50) V = W_ih[row];
                    else if (k == 51) V = b_ih[row] + b_hh[row];
                }
                h8[i] = (_Float16)(V * scl);    // single fp16 product (RNE)
            }
            wh[q2] = h8;
        }
    }

    // ---- init h: zeros both bufs; k=50 buf0 <- fp16(x(b,0)); k=51 <- 1.0 both
    for (int i = tid; i < HSZ; i += NTH)       // HSZ uints = 2*HSZ halfs
        ((unsigned int*)Hh)[i] = 0u;
    __syncthreads();
    if (tid < MB) {
        float xv = x[(bbase + tid) * TST + 0];
        Hh[tid * HR + 50] = f16bits(xv);
        Hh[tid * HR + 51] = 0x3C00;            // fp16(1.0), never rewritten
        Hh[HSZ + tid * HR + 51] = 0x3C00;
    }
    __syncthreads();

    // ---- anti-phase skew: half of each co-resident block pair sleeps
    // ~576 cyc (~half a step) so the two blocks' per-step serial tails
    // interleave with each other's trans-issue bursts instead of
    // phase-locking in-phase. Key covers (b,b+256) and (2b,2b+1) pairings.
    if ((((blockIdx.x >> 8) ^ blockIdx.x) & 1) != 0)
        __builtin_amdgcn_s_sleep(9);

    float c2 = 0.0f;                           // c in the x2log2e domain
    const unsigned short* Hr = &Hh[lrow * HR + quad * 8];  // frag read base
    int jw = T * 4 + quad;                                 // unit this lane writes
    if (jw >= 50) jw = 52 + quad;                          // pad redirect (54/55)
    unsigned short* Hw = &Hh[lrow * HR + jw];              // write base (hoisted)
    const float* xr = &x[(bbase + lrow) * TST];            // x-wave read row
    const float4v z4 = {0.f, 0.f, 0.f, 0.f};               // zero C operand

    // one compute step; roff/woff compile-time after inlining -> imm offsets
    auto step1 = [&](int roff, int woff) {
        const half8 b0 = *(const half8*)(Hr + roff);
        const half8 b1 = *(const half8*)(Hr + roff + 32);

        float4v a4;
        a4 = __builtin_amdgcn_mfma_f32_16x16x32_f16(wh[0], b0, z4, 0, 0, 0);
        a4 = __builtin_amdgcn_mfma_f32_16x16x32_f16(wh[1], b1, a4, 0, 0, 0);

        // a4 = (ai,af,ag,ao): i/f/o pre-scaled by -L, g by +2L.
        const float Ei = exp2_(a4[0]);
        const float Ef = exp2_(a4[1]);
        const float Eg = exp2_(a4[2]);
        const float Eo = exp2_(a4[3]);
        // c2' = f*c2 + i*(2L*tanh_g) with ONE rcp:
        const float D1 = 1.0f + Ef;
        const float D2 = (Eg + 1.0f) * (1.0f + Ei);
        const float R  = rcp_(D1 * D2);
        const float tg = (Eg - 1.0f) * D1;
        const float nm = fmaf(2.0f * LOG2E, tg, c2 * D2);
        c2 = fminf(nm * R, 120.0f);            // clamp: exp2 overflow guard
        // h = tanh(c)*sigmoid(ao) with ONE rcp:
        const float Ec = exp2_(c2);
        const float R2 = rcp_((Ec + 1.0f) * (1.0f + Eo));
        const float hn = (Ec - 1.0f) * R2;

        Hw[woff] = f16bits(hn);                // unconditional (pad-redirected)
    };

    #pragma unroll 1
    for (int t2 = 0; t2 < TST / 2; ++t2) {
        if (wv == 13) {
            // x-wave: prefetch both x values at iteration top (latency hidden),
            // publish fp16(x(t+1)) into the buffer the NEXT step will read.
            const float xA = xr[2 * t2 + 1];
            const float xB = xr[(2 * t2 + 2) & 255];   // t2=127: never read
            if (ln < 16)
                Hh[HSZ + lrow * HR + 50] = f16bits(xA);   // buf1 <- x(odd step)
            __syncthreads();                   // barrier 1 (even step done)
            if (ln < 16)
                Hh[lrow * HR + 50] = f16bits(xB);         // buf0 <- x(even step)
            __syncthreads();                   // barrier 2 (odd step done)
        } else {
            step1(0, HSZ);                     // even: read buf0, write buf1
            __syncthreads();
            step1(HSZ, 0);                     // odd:  read buf1, write buf0
            __syncthreads();
        }
    }

    // ---- epilogue: final h in buf 0 (t=255 wrote buf0)
    if (tid < MB) {
        float s = b_lin[0];
        #pragma unroll 10
        for (int k = 0; k < 50; ++k) {
            float hk = (float)(*(const _Float16*)&Hh[tid * HR + k]);
            s += hk * W_lin[k];
        }
        out[bbase + tid] = s;
    }
}

extern "C" void kernel_launch(void* const* d_in, const int* in_sizes, int n_in,
                              void* d_out, int out_size, void* d_ws, size_t ws_size,
                              hipStream_t stream) {
    const float* x     = (const float*)d_in[0];
    const float* W_ih  = (const float*)d_in[1];
    const float* W_hh  = (const float*)d_in[2];
    const float* b_ih  = (const float*)d_in[3];
    const float* b_hh  = (const float*)d_in[4];
    const float* W_lin = (const float*)d_in[5];
    const float* b_lin = (const float*)d_in[6];
    float* out = (float*)d_out;

    lstm_mfma<<<dim3(NBLK), dim3(NTH), 0, stream>>>(
        x, W_ih, W_hh, b_ih, b_hh, W_lin, b_lin, out);
}